// Round 1
// 1010.270 us; speedup vs baseline: 1.0278x; 1.0278x over previous
//
#include <hip/hip_runtime.h>

#define E 8
#define T 2048
#define D 1024
#define H 4096

using f32x4 = __attribute__((ext_vector_type(4))) float;
using frag8 = __attribute__((ext_vector_type(8))) short;  // 8 bf16 in 4 VGPRs

typedef unsigned int uint_as3 __attribute__((address_space(3)));
typedef unsigned int uint_as1 __attribute__((address_space(1)));

__device__ __forceinline__ unsigned short f2bf(float f) {
  unsigned int u = __float_as_uint(f);
  u += 0x7fffu + ((u >> 16) & 1u);  // round-to-nearest-even
  return (unsigned short)(u >> 16);
}

__device__ __forceinline__ void gload16(const void* g, void* l) {
  __builtin_amdgcn_global_load_lds((const uint_as1*)g, (uint_as3*)l, 16, 0, 0);
}

// Stage 8 rows x 64 cols bf16 starting at row r0, one full wave (64 lanes x 16B).
// XOR-swizzle: LDS slot (row, cs) holds global chunk cs ^ (row&7). Since the
// LDS dest of global_load_lds is forced to base+lane*16, we permute the GLOBAL
// source chunk per lane instead. Verified: 0 bank conflicts in rocprof.
__device__ __forceinline__ void stage8(const unsigned short* src, int ld,
                                       unsigned short* lds, int r0, int lane) {
  int lr = lane >> 3;       // row within the 8-row chunk
  int cs = lane & 7;        // LDS chunk slot
  int gc = cs ^ lr;         // swizzled global chunk
  const unsigned short* g = src + (size_t)(r0 + lr) * ld + gc * 8;
  unsigned short* l = lds + r0 * 64;  // wave-uniform base
  gload16(g, l);
}

// Read a K-contiguous 8-elem bf16 fragment for `row` at chunk index, undoing
// the swizzle. 2-way bank aliasing only -> conflict-free (measured 0).
__device__ __forceinline__ frag8 read_frag(const unsigned short* lds, int row, int chunk) {
  return *(const frag8*)&lds[row * 64 + ((chunk ^ (row & 7)) << 3)];
}

#define BARRIER() asm volatile("s_barrier" ::: "memory")
#define WAIT_LGKM0() asm volatile("s_waitcnt lgkmcnt(0)" ::: "memory")

// ---------------- pass 0: convert / transpose-convert to bf16 ----------------

__global__ __launch_bounds__(256) void convert_kernel(const float4* __restrict__ in,
                                                      ushort4* __restrict__ out, int n4) {
  int i = blockIdx.x * blockDim.x + threadIdx.x;
  int stride = gridDim.x * blockDim.x;
  for (; i < n4; i += stride) {
    float4 v = in[i];
    ushort4 o;
    o.x = f2bf(v.x); o.y = f2bf(v.y); o.z = f2bf(v.z); o.w = f2bf(v.w);
    out[i] = o;
  }
}

// per-expert [R,C] fp32 -> [C,R] bf16.  grid: (C/32, R/32, E), block (32,8)
__global__ __launch_bounds__(256) void tconv_kernel(const float* __restrict__ in,
                                                    unsigned short* __restrict__ out,
                                                    int R, int C) {
  __shared__ float tile[32][33];
  int e = blockIdx.z;
  const float* src = in + (size_t)e * R * C;
  unsigned short* dst = out + (size_t)e * R * C;
  int c0 = blockIdx.x * 32, r0 = blockIdx.y * 32;
  int tx = threadIdx.x, ty = threadIdx.y;
#pragma unroll
  for (int i = 0; i < 32; i += 8)
    tile[ty + i][tx] = src[(size_t)(r0 + ty + i) * C + c0 + tx];
  __syncthreads();
#pragma unroll
  for (int i = 0; i < 32; i += 8)
    dst[(size_t)(c0 + ty + i) * R + r0 + tx] = f2bf(tile[tx][ty + i]);
}

// ---------------- GEMM1: og = (x@Wfc + bfc) * silu(x@Wg + bg) ----------------
// 3-slot LDS ring, counted vmcnt, 2 phases/K-tile, 8 waves.
// BM=128 (M), BN=128 (cols of both h and g). Waves 2M x 4N, per-wave 64x32 of
// BOTH h and g: acc = 2*(4x2)*4 = 64 VGPR; 32 MFMA / K-tile / wave.
// Schedule invariant (race-free):
//   iter t reads slot t%3; iter t stages tile t+2 into slot (t+2)%3.
//   Slot (t+2)%3's last reads were iter t-1, sealed by its final barrier.
//   End-of-iter vmcnt(6) leaves exactly tile t+2's 6 loads in flight ->
//   tile t+1 (needed next iter) is landed; barrier makes it block-wide.

__global__ __launch_bounds__(512) void gemm1_kernel(
    const unsigned short* __restrict__ xb,
    const unsigned short* __restrict__ wfcT,
    const unsigned short* __restrict__ wgT,
    const float* __restrict__ bfc,
    const float* __restrict__ bgate,
    unsigned short* __restrict__ og) {
  __shared__ unsigned short As[3][128 * 64];  // 3 x 16 KB
  __shared__ unsigned short Bf[3][128 * 64];  // 3 x 16 KB
  __shared__ unsigned short Bg[3][128 * 64];  // 3 x 16 KB   total 144 KB

  int bid = blockIdx.x;
  int e = bid >> 9;           // 512 blocks/expert
  int mt = (bid >> 5) & 15;   // T/128 = 16
  int nt = bid & 31;          // H/128 = 32
  int m0 = mt * 128, n0 = nt * 128;

  int tid = threadIdx.x;
  int w = __builtin_amdgcn_readfirstlane(tid >> 6);
  int lane = tid & 63;

  const unsigned short* Ab = xb + (size_t)e * T * D + (size_t)m0 * D;
  const unsigned short* Fb = wfcT + (size_t)e * H * D + (size_t)n0 * D;
  const unsigned short* Gb = wgT + (size_t)e * H * D + (size_t)n0 * D;

  f32x4 ah[4][2] = {};
  f32x4 ag[4][2] = {};

  int wm = (w >> 2) * 64;   // 0 or 64
  int wn = (w & 3) * 32;    // 0,32,64,96
  int col = lane & 15, quad = lane >> 4;
  int r0a = w * 8;          // per-wave staging row base

  constexpr int NT = D / 64;  // 16 K-tiles

  // prologue: fully stage tiles 0,1 into slots 0,1 (6 loads each, in order)
#pragma unroll
  for (int t0 = 0; t0 < 2; ++t0) {
    stage8(Ab + t0 * 64, D, As[t0], r0a, lane);
    stage8(Ab + t0 * 64, D, As[t0], r0a + 64, lane);
    stage8(Fb + t0 * 64, D, Bf[t0], r0a, lane);
    stage8(Fb + t0 * 64, D, Bf[t0], r0a + 64, lane);
    stage8(Gb + t0 * 64, D, Bg[t0], r0a, lane);
    stage8(Gb + t0 * 64, D, Bg[t0], r0a + 64, lane);
  }
  asm volatile("s_waitcnt vmcnt(6)" ::: "memory");  // tile 0 landed, tile 1 in flight
  BARRIER();

  int s = 0, s2 = 2;
  for (int t = 0; t < NT; ++t) {
    const unsigned short* Asl = As[s];
    const unsigned short* Bfl = Bf[s];
    const unsigned short* Bgl = Bg[s];
    bool pf = (t + 2) < NT;
    int kpre = (t + 2) * 64;

    // ---- phase 0 (kk = 0..31) ----
    frag8 a[4], f[2], g[2];
#pragma unroll
    for (int i = 0; i < 4; ++i) a[i] = read_frag(Asl, wm + i * 16 + col, quad);
#pragma unroll
    for (int i = 0; i < 2; ++i) {
      f[i] = read_frag(Bfl, wn + i * 16 + col, quad);
      g[i] = read_frag(Bgl, wn + i * 16 + col, quad);
    }
    if (pf) {
      stage8(Ab + kpre, D, As[s2], r0a, lane);
      stage8(Ab + kpre, D, As[s2], r0a + 64, lane);
      stage8(Fb + kpre, D, Bf[s2], r0a, lane);
    }
    BARRIER();
    WAIT_LGKM0();
    __builtin_amdgcn_sched_barrier(0);
    __builtin_amdgcn_s_setprio(1);
#pragma unroll
    for (int mi = 0; mi < 4; ++mi)
#pragma unroll
      for (int ni = 0; ni < 2; ++ni) {
        ah[mi][ni] = __builtin_amdgcn_mfma_f32_16x16x32_bf16(a[mi], f[ni], ah[mi][ni], 0, 0, 0);
        ag[mi][ni] = __builtin_amdgcn_mfma_f32_16x16x32_bf16(a[mi], g[ni], ag[mi][ni], 0, 0, 0);
      }
    __builtin_amdgcn_s_setprio(0);
    BARRIER();

    // ---- phase 1 (kk = 32..63) ----
#pragma unroll
    for (int i = 0; i < 4; ++i) a[i] = read_frag(Asl, wm + i * 16 + col, 4 + quad);
#pragma unroll
    for (int i = 0; i < 2; ++i) {
      f[i] = read_frag(Bfl, wn + i * 16 + col, 4 + quad);
      g[i] = read_frag(Bgl, wn + i * 16 + col, 4 + quad);
    }
    if (pf) {
      stage8(Fb + kpre, D, Bf[s2], r0a + 64, lane);
      stage8(Gb + kpre, D, Bg[s2], r0a, lane);
      stage8(Gb + kpre, D, Bg[s2], r0a + 64, lane);
    }
    BARRIER();
    WAIT_LGKM0();
    __builtin_amdgcn_sched_barrier(0);
    __builtin_amdgcn_s_setprio(1);
#pragma unroll
    for (int mi = 0; mi < 4; ++mi)
#pragma unroll
      for (int ni = 0; ni < 2; ++ni) {
        ah[mi][ni] = __builtin_amdgcn_mfma_f32_16x16x32_bf16(a[mi], f[ni], ah[mi][ni], 0, 0, 0);
        ag[mi][ni] = __builtin_amdgcn_mfma_f32_16x16x32_bf16(a[mi], g[ni], ag[mi][ni], 0, 0, 0);
      }
    __builtin_amdgcn_s_setprio(0);
    if (pf)
      asm volatile("s_waitcnt vmcnt(6)" ::: "memory");   // tile t+1 landed
    else if (t + 2 == NT)
      asm volatile("s_waitcnt vmcnt(0)" ::: "memory");   // drain last tile
    BARRIER();

    s = (s == 2) ? 0 : s + 1;
    s2 = (s2 == 2) ? 0 : s2 + 1;
  }

  // epilogue: bias + silu gate + product, write og bf16
#pragma unroll
  for (int ni = 0; ni < 2; ++ni) {
    int n = n0 + wn + ni * 16 + col;
    float bh = bfc[e * H + n];
    float bg2 = bgate[e * H + n];
#pragma unroll
    for (int mi = 0; mi < 4; ++mi) {
#pragma unroll
      for (int i = 0; i < 4; ++i) {
        int m = m0 + wm + mi * 16 + quad * 4 + i;
        float hv = ah[mi][ni][i] + bh;
        float gv = ag[mi][ni][i] + bg2;
        float sg = gv / (1.0f + __expf(-gv));
        og[(size_t)e * T * H + (size_t)m * H + n] = f2bf(hv * sg);
      }
    }
  }
}

// ---------------- GEMM2: out = og @ Wproj + bproj (fp32 out) ----------------
// Same 3-slot ring / counted-vmcnt schedule. BM=256, BN=128, 8 waves 4M x 2N,
// per-wave 64x64: acc 64 VGPR, 32 MFMA / K-tile / wave. NT = 64.

__global__ __launch_bounds__(512) void gemm2_kernel(
    const unsigned short* __restrict__ og,
    const unsigned short* __restrict__ wpT,
    const float* __restrict__ bproj,
    float* __restrict__ out) {
  __shared__ unsigned short As[3][256 * 64];  // 3 x 32 KB
  __shared__ unsigned short Bs[3][128 * 64];  // 3 x 16 KB   total 144 KB

  int bid = blockIdx.x;
  int e = bid >> 6;           // 64 blocks/expert
  int mt = (bid >> 3) & 7;    // T/256 = 8
  int nt = bid & 7;           // D/128 = 8
  int m0 = mt * 256, n0 = nt * 128;

  int tid = threadIdx.x;
  int w = __builtin_amdgcn_readfirstlane(tid >> 6);
  int lane = tid & 63;

  const unsigned short* Ab = og + (size_t)e * T * H + (size_t)m0 * H;
  const unsigned short* Bb = wpT + (size_t)e * D * H + (size_t)n0 * H;

  f32x4 acc[4][4] = {};

  int wm = (w >> 1) * 64;   // 0,64,128,192
  int wn = (w & 1) * 64;    // 0,64
  int col = lane & 15, quad = lane >> 4;
  int r0a = w * 8;

  constexpr int NT = H / 64;  // 64 K-tiles

  // prologue: stage tiles 0,1 into slots 0,1 (6 loads each, in order)
#pragma unroll
  for (int t0 = 0; t0 < 2; ++t0) {
    stage8(Ab + t0 * 64, H, As[t0], r0a, lane);
    stage8(Ab + t0 * 64, H, As[t0], r0a + 64, lane);
    stage8(Ab + t0 * 64, H, As[t0], r0a + 128, lane);
    stage8(Ab + t0 * 64, H, As[t0], r0a + 192, lane);
    stage8(Bb + t0 * 64, H, Bs[t0], r0a, lane);
    stage8(Bb + t0 * 64, H, Bs[t0], r0a + 64, lane);
  }
  asm volatile("s_waitcnt vmcnt(6)" ::: "memory");
  BARRIER();

  int s = 0, s2 = 2;
  for (int t = 0; t < NT; ++t) {
    const unsigned short* Asl = As[s];
    const unsigned short* Bsl = Bs[s];
    bool pf = (t + 2) < NT;
    int kpre = (t + 2) * 64;

    // ---- phase 0 (kk = 0..31) ----
    frag8 a[4], b[4];
#pragma unroll
    for (int i = 0; i < 4; ++i) a[i] = read_frag(Asl, wm + i * 16 + col, quad);
#pragma unroll
    for (int i = 0; i < 4; ++i) b[i] = read_frag(Bsl, wn + i * 16 + col, quad);
    if (pf) {
      stage8(Ab + kpre, H, As[s2], r0a, lane);
      stage8(Ab + kpre, H, As[s2], r0a + 64, lane);
      stage8(Bb + kpre, H, Bs[s2], r0a, lane);
    }
    BARRIER();
    WAIT_LGKM0();
    __builtin_amdgcn_sched_barrier(0);
    __builtin_amdgcn_s_setprio(1);
#pragma unroll
    for (int mi = 0; mi < 4; ++mi)
#pragma unroll
      for (int ni = 0; ni < 4; ++ni)
        acc[mi][ni] = __builtin_amdgcn_mfma_f32_16x16x32_bf16(a[mi], b[ni], acc[mi][ni], 0, 0, 0);
    __builtin_amdgcn_s_setprio(0);
    BARRIER();

    // ---- phase 1 (kk = 32..63) ----
#pragma unroll
    for (int i = 0; i < 4; ++i) a[i] = read_frag(Asl, wm + i * 16 + col, 4 + quad);
#pragma unroll
    for (int i = 0; i < 4; ++i) b[i] = read_frag(Bsl, wn + i * 16 + col, 4 + quad);
    if (pf) {
      stage8(Ab + kpre, H, As[s2], r0a + 128, lane);
      stage8(Ab + kpre, H, As[s2], r0a + 192, lane);
      stage8(Bb + kpre, H, Bs[s2], r0a + 64, lane);
    }
    BARRIER();
    WAIT_LGKM0();
    __builtin_amdgcn_sched_barrier(0);
    __builtin_amdgcn_s_setprio(1);
#pragma unroll
    for (int mi = 0; mi < 4; ++mi)
#pragma unroll
      for (int ni = 0; ni < 4; ++ni)
        acc[mi][ni] = __builtin_amdgcn_mfma_f32_16x16x32_bf16(a[mi], b[ni], acc[mi][ni], 0, 0, 0);
    __builtin_amdgcn_s_setprio(0);
    if (pf)
      asm volatile("s_waitcnt vmcnt(6)" ::: "memory");
    else if (t + 2 == NT)
      asm volatile("s_waitcnt vmcnt(0)" ::: "memory");
    BARRIER();

    s = (s == 2) ? 0 : s + 1;
    s2 = (s2 == 2) ? 0 : s2 + 1;
  }

#pragma unroll
  for (int ni = 0; ni < 4; ++ni) {
    int n = n0 + wn + ni * 16 + col;
    float bb = bproj[e * D + n];
#pragma unroll
    for (int mi = 0; mi < 4; ++mi) {
#pragma unroll
      for (int i = 0; i < 4; ++i) {
        int m = m0 + wm + mi * 16 + quad * 4 + i;
        out[(size_t)e * T * D + (size_t)m * D + n] = acc[mi][ni][i] + bb;
      }
    }
  }
}

// ---------------------------------------------------------------------------

extern "C" void kernel_launch(void* const* d_in, const int* in_sizes, int n_in,
                              void* d_out, int out_size, void* d_ws, size_t ws_size,
                              hipStream_t stream) {
  const float* x = (const float*)d_in[0];
  const float* wfc = (const float*)d_in[1];
  const float* bfc = (const float*)d_in[2];
  const float* wg = (const float*)d_in[3];
  const float* bg = (const float*)d_in[4];
  const float* wp = (const float*)d_in[5];
  const float* bp = (const float*)d_in[6];
  float* out = (float*)d_out;

  char* ws = (char*)d_ws;
  // ws layout (bytes): xb 32MB | wfcT 64MB | wgT 64MB | wpT 64MB | og 128MB
  unsigned short* xb = (unsigned short*)(ws);
  unsigned short* wfcT = (unsigned short*)(ws + 33554432);
  unsigned short* wgT = (unsigned short*)(ws + 100663296);
  unsigned short* wpT = (unsigned short*)(ws + 167772160);
  unsigned short* og = (unsigned short*)(ws + 234881024);

  convert_kernel<<<2048, 256, 0, stream>>>((const float4*)x, (ushort4*)xb,
                                           (int)((size_t)E * T * D / 4));
  tconv_kernel<<<dim3(H / 32, D / 32, E), dim3(32, 8), 0, stream>>>(wfc, wfcT, D, H);
  tconv_kernel<<<dim3(H / 32, D / 32, E), dim3(32, 8), 0, stream>>>(wg, wgT, D, H);
  tconv_kernel<<<dim3(D / 32, H / 32, E), dim3(32, 8), 0, stream>>>(wp, wpT, H, D);

  gemm1_kernel<<<E * (T / 128) * (H / 128), 512, 0, stream>>>(xb, wfcT, wgT, bfc, bg, og);
  gemm2_kernel<<<E * (T / 256) * (D / 128), 512, 0, stream>>>(og, wpT, bp, out);
}

// Round 2
// 883.696 us; speedup vs baseline: 1.1751x; 1.1432x over previous
//
#include <hip/hip_runtime.h>

#define E 8
#define T 2048
#define D 1024
#define H 4096

using f32x4 = __attribute__((ext_vector_type(4))) float;
using frag8 = __attribute__((ext_vector_type(8))) short;  // 8 bf16 in 4 VGPRs

typedef unsigned int uint_as3 __attribute__((address_space(3)));
typedef unsigned int uint_as1 __attribute__((address_space(1)));

__device__ __forceinline__ unsigned short f2bf(float f) {
  unsigned int u = __float_as_uint(f);
  u += 0x7fffu + ((u >> 16) & 1u);  // round-to-nearest-even
  return (unsigned short)(u >> 16);
}

__device__ __forceinline__ void gload16(const void* g, void* l) {
  __builtin_amdgcn_global_load_lds((const uint_as1*)g, (uint_as3*)l, 16, 0, 0);
}

// Stage 8 rows x 64 cols bf16 starting at row r0, one full wave (64 lanes x 16B).
// XOR-swizzle: LDS slot (row, cs) holds global chunk cs ^ (row&7). Since the
// LDS dest of global_load_lds is forced to base+lane*16, we permute the GLOBAL
// source chunk per lane instead. Verified: 0 bank conflicts in rocprof.
__device__ __forceinline__ void stage8(const unsigned short* src, int ld,
                                       unsigned short* lds, int r0, int lane) {
  int lr = lane >> 3;       // row within the 8-row chunk
  int cs = lane & 7;        // LDS chunk slot
  int gc = cs ^ lr;         // swizzled global chunk
  const unsigned short* g = src + (size_t)(r0 + lr) * ld + gc * 8;
  unsigned short* l = lds + r0 * 64;  // wave-uniform base
  gload16(g, l);
}

// Read a K-contiguous 8-elem bf16 fragment for `row` at chunk index, undoing
// the swizzle. 2-way bank aliasing only -> conflict-free (measured 0).
__device__ __forceinline__ frag8 read_frag(const unsigned short* lds, int row, int chunk) {
  return *(const frag8*)&lds[row * 64 + ((chunk ^ (row & 7)) << 3)];
}

#define BARRIER() asm volatile("s_barrier" ::: "memory")

// ---------------- pass 0: convert / transpose-convert to bf16 ----------------

__global__ __launch_bounds__(256) void convert_kernel(const float4* __restrict__ in,
                                                      ushort4* __restrict__ out, int n4) {
  int i = blockIdx.x * blockDim.x + threadIdx.x;
  int stride = gridDim.x * blockDim.x;
  for (; i < n4; i += stride) {
    float4 v = in[i];
    ushort4 o;
    o.x = f2bf(v.x); o.y = f2bf(v.y); o.z = f2bf(v.z); o.w = f2bf(v.w);
    out[i] = o;
  }
}

// per-expert [R,C] fp32 -> [C,R] bf16.  grid: (C/32, R/32, E), block (32,8)
__global__ __launch_bounds__(256) void tconv_kernel(const float* __restrict__ in,
                                                    unsigned short* __restrict__ out,
                                                    int R, int C) {
  __shared__ float tile[32][33];
  int e = blockIdx.z;
  const float* src = in + (size_t)e * R * C;
  unsigned short* dst = out + (size_t)e * R * C;
  int c0 = blockIdx.x * 32, r0 = blockIdx.y * 32;
  int tx = threadIdx.x, ty = threadIdx.y;
#pragma unroll
  for (int i = 0; i < 32; i += 8)
    tile[ty + i][tx] = src[(size_t)(r0 + ty + i) * C + c0 + tx];
  __syncthreads();
#pragma unroll
  for (int i = 0; i < 32; i += 8)
    dst[(size_t)(c0 + ty + i) * R + r0 + tx] = f2bf(tile[tx][ty + i]);
}

// ---------------- GEMM1: og = (x@Wfc + bfc) * silu(x@Wg + bg) ----------------
// 3-slot LDS ring, counted vmcnt, ONE barrier per K-tile, 8 waves.
// BM=128, BN=128 (cols of both h and g). Waves 2M x 4N, per-wave 64x32 of BOTH.
// Ring invariant (race-free with a single end-of-iter barrier):
//   iter t reads slot t%3, stages tile t+2 into slot (t+2)%3.
//   Slot (t+2)%3's last readers were iter t-1; their ds_reads complete (compiler
//   lgkmcnt) before they reach iter t-1's barrier, and iter t's stage8 is issued
//   after that barrier -> no read/write race.
//   End-of-iter vmcnt(6) leaves exactly tile t+2's 6 loads in flight -> tile
//   t+1 is landed; the barrier publishes it block-wide.
// No mid barriers: waves skew, one wave's MFMA overlaps another's LDS waits.

__global__ __launch_bounds__(512) void gemm1_kernel(
    const unsigned short* __restrict__ xb,
    const unsigned short* __restrict__ wfcT,
    const unsigned short* __restrict__ wgT,
    const float* __restrict__ bfc,
    const float* __restrict__ bgate,
    unsigned short* __restrict__ og) {
  __shared__ unsigned short As[3][128 * 64];  // 3 x 16 KB
  __shared__ unsigned short Bf[3][128 * 64];  // 3 x 16 KB
  __shared__ unsigned short Bg[3][128 * 64];  // 3 x 16 KB   total 144 KB

  int bid = blockIdx.x;
  int e = bid >> 9;           // 512 blocks/expert
  int mt = (bid >> 5) & 15;   // T/128 = 16
  int nt = bid & 31;          // H/128 = 32
  int m0 = mt * 128, n0 = nt * 128;

  int tid = threadIdx.x;
  int w = __builtin_amdgcn_readfirstlane(tid >> 6);
  int lane = tid & 63;

  const unsigned short* Ab = xb + (size_t)e * T * D + (size_t)m0 * D;
  const unsigned short* Fb = wfcT + (size_t)e * H * D + (size_t)n0 * D;
  const unsigned short* Gb = wgT + (size_t)e * H * D + (size_t)n0 * D;

  f32x4 ah[4][2] = {};
  f32x4 ag[4][2] = {};

  int wm = (w >> 2) * 64;   // 0 or 64
  int wn = (w & 3) * 32;    // 0,32,64,96
  int col = lane & 15, quad = lane >> 4;
  int r0a = w * 8;          // per-wave staging row base

  constexpr int NT = D / 64;  // 16 K-tiles

  // prologue: fully stage tiles 0,1 into slots 0,1 (6 loads each, in order)
#pragma unroll
  for (int t0 = 0; t0 < 2; ++t0) {
    stage8(Ab + t0 * 64, D, As[t0], r0a, lane);
    stage8(Ab + t0 * 64, D, As[t0], r0a + 64, lane);
    stage8(Fb + t0 * 64, D, Bf[t0], r0a, lane);
    stage8(Fb + t0 * 64, D, Bf[t0], r0a + 64, lane);
    stage8(Gb + t0 * 64, D, Bg[t0], r0a, lane);
    stage8(Gb + t0 * 64, D, Bg[t0], r0a + 64, lane);
  }
  asm volatile("s_waitcnt vmcnt(6)" ::: "memory");  // tile 0 landed, tile 1 in flight
  BARRIER();

  int s = 0, s2 = 2;
  for (int t = 0; t < NT; ++t) {
    const unsigned short* Asl = As[s];
    const unsigned short* Bfl = Bf[s];
    const unsigned short* Bgl = Bg[s];
    bool pf = (t + 2) < NT;
    int kpre = (t + 2) * 64;

    // issue all frag reads for both phases (compiler inserts counted lgkmcnt)
    frag8 a0[4], f0[2], g0[2], a1[4], f1[2], g1[2];
#pragma unroll
    for (int i = 0; i < 4; ++i) {
      a0[i] = read_frag(Asl, wm + i * 16 + col, quad);
      a1[i] = read_frag(Asl, wm + i * 16 + col, 4 + quad);
    }
#pragma unroll
    for (int i = 0; i < 2; ++i) {
      f0[i] = read_frag(Bfl, wn + i * 16 + col, quad);
      f1[i] = read_frag(Bfl, wn + i * 16 + col, 4 + quad);
      g0[i] = read_frag(Bgl, wn + i * 16 + col, quad);
      g1[i] = read_frag(Bgl, wn + i * 16 + col, 4 + quad);
    }
    // prefetch tile t+2 into slot s2 (vmcnt-tracked, rides across barriers)
    if (pf) {
      stage8(Ab + kpre, D, As[s2], r0a, lane);
      stage8(Ab + kpre, D, As[s2], r0a + 64, lane);
      stage8(Fb + kpre, D, Bf[s2], r0a, lane);
      stage8(Fb + kpre, D, Bf[s2], r0a + 64, lane);
      stage8(Gb + kpre, D, Bg[s2], r0a, lane);
      stage8(Gb + kpre, D, Bg[s2], r0a + 64, lane);
    }
    __builtin_amdgcn_s_setprio(1);
#pragma unroll
    for (int mi = 0; mi < 4; ++mi)
#pragma unroll
      for (int ni = 0; ni < 2; ++ni) {
        ah[mi][ni] = __builtin_amdgcn_mfma_f32_16x16x32_bf16(a0[mi], f0[ni], ah[mi][ni], 0, 0, 0);
        ag[mi][ni] = __builtin_amdgcn_mfma_f32_16x16x32_bf16(a0[mi], g0[ni], ag[mi][ni], 0, 0, 0);
      }
#pragma unroll
    for (int mi = 0; mi < 4; ++mi)
#pragma unroll
      for (int ni = 0; ni < 2; ++ni) {
        ah[mi][ni] = __builtin_amdgcn_mfma_f32_16x16x32_bf16(a1[mi], f1[ni], ah[mi][ni], 0, 0, 0);
        ag[mi][ni] = __builtin_amdgcn_mfma_f32_16x16x32_bf16(a1[mi], g1[ni], ag[mi][ni], 0, 0, 0);
      }
    __builtin_amdgcn_s_setprio(0);

    if (pf)
      asm volatile("s_waitcnt vmcnt(6)" ::: "memory");   // tile t+1 landed
    else if (t + 2 == NT)
      asm volatile("s_waitcnt vmcnt(0)" ::: "memory");   // drain last tile
    BARRIER();

    s = (s == 2) ? 0 : s + 1;
    s2 = (s2 == 2) ? 0 : s2 + 1;
  }

  // epilogue: bias + silu gate + product, write og bf16
#pragma unroll
  for (int ni = 0; ni < 2; ++ni) {
    int n = n0 + wn + ni * 16 + col;
    float bh = bfc[e * H + n];
    float bg2 = bgate[e * H + n];
#pragma unroll
    for (int mi = 0; mi < 4; ++mi) {
#pragma unroll
      for (int i = 0; i < 4; ++i) {
        int m = m0 + wm + mi * 16 + quad * 4 + i;
        float hv = ah[mi][ni][i] + bh;
        float gv = ag[mi][ni][i] + bg2;
        float sg = gv / (1.0f + __expf(-gv));
        og[(size_t)e * T * H + (size_t)m * H + n] = f2bf(hv * sg);
      }
    }
  }
}

// ---------------- GEMM2: out = og @ Wproj + bproj (fp32 out) ----------------
// Same 3-slot ring / single-barrier schedule. BM=256, BN=128, 8 waves 4M x 2N,
// per-wave 64x64. XCD swizzle: 512 blocks, bid&7 = XCD = expert -> each XCD's
// working set is one expert's og (16MB) + wpT (8MB), L3-resident.

__global__ __launch_bounds__(512) void gemm2_kernel(
    const unsigned short* __restrict__ og,
    const unsigned short* __restrict__ wpT,
    const float* __restrict__ bproj,
    float* __restrict__ out) {
  __shared__ unsigned short As[3][256 * 64];  // 3 x 32 KB
  __shared__ unsigned short Bs[3][128 * 64];  // 3 x 16 KB   total 144 KB

  int bid = blockIdx.x;
  int e = bid & 7;            // XCD-aligned: one expert per XCD
  int idx = bid >> 3;         // 0..63
  int mt = idx >> 3;          // T/256 = 8
  int nt = idx & 7;           // D/128 = 8
  int m0 = mt * 256, n0 = nt * 128;

  int tid = threadIdx.x;
  int w = __builtin_amdgcn_readfirstlane(tid >> 6);
  int lane = tid & 63;

  const unsigned short* Ab = og + (size_t)e * T * H + (size_t)m0 * H;
  const unsigned short* Bb = wpT + (size_t)e * D * H + (size_t)n0 * H;

  f32x4 acc[4][4] = {};

  int wm = (w >> 1) * 64;   // 0,64,128,192
  int wn = (w & 1) * 64;    // 0,64
  int col = lane & 15, quad = lane >> 4;
  int r0a = w * 8;

  constexpr int NT = H / 64;  // 64 K-tiles

  // prologue: stage tiles 0,1 into slots 0,1 (6 loads each, in order)
#pragma unroll
  for (int t0 = 0; t0 < 2; ++t0) {
    stage8(Ab + t0 * 64, H, As[t0], r0a, lane);
    stage8(Ab + t0 * 64, H, As[t0], r0a + 64, lane);
    stage8(Ab + t0 * 64, H, As[t0], r0a + 128, lane);
    stage8(Ab + t0 * 64, H, As[t0], r0a + 192, lane);
    stage8(Bb + t0 * 64, H, Bs[t0], r0a, lane);
    stage8(Bb + t0 * 64, H, Bs[t0], r0a + 64, lane);
  }
  asm volatile("s_waitcnt vmcnt(6)" ::: "memory");
  BARRIER();

  int s = 0, s2 = 2;
  for (int t = 0; t < NT; ++t) {
    const unsigned short* Asl = As[s];
    const unsigned short* Bsl = Bs[s];
    bool pf = (t + 2) < NT;
    int kpre = (t + 2) * 64;

    frag8 a0[4], b0[4], a1[4], b1[4];
#pragma unroll
    for (int i = 0; i < 4; ++i) {
      a0[i] = read_frag(Asl, wm + i * 16 + col, quad);
      a1[i] = read_frag(Asl, wm + i * 16 + col, 4 + quad);
      b0[i] = read_frag(Bsl, wn + i * 16 + col, quad);
      b1[i] = read_frag(Bsl, wn + i * 16 + col, 4 + quad);
    }
    if (pf) {
      stage8(Ab + kpre, H, As[s2], r0a, lane);
      stage8(Ab + kpre, H, As[s2], r0a + 64, lane);
      stage8(Ab + kpre, H, As[s2], r0a + 128, lane);
      stage8(Ab + kpre, H, As[s2], r0a + 192, lane);
      stage8(Bb + kpre, H, Bs[s2], r0a, lane);
      stage8(Bb + kpre, H, Bs[s2], r0a + 64, lane);
    }
    __builtin_amdgcn_s_setprio(1);
#pragma unroll
    for (int mi = 0; mi < 4; ++mi)
#pragma unroll
      for (int ni = 0; ni < 4; ++ni)
        acc[mi][ni] = __builtin_amdgcn_mfma_f32_16x16x32_bf16(a0[mi], b0[ni], acc[mi][ni], 0, 0, 0);
#pragma unroll
    for (int mi = 0; mi < 4; ++mi)
#pragma unroll
      for (int ni = 0; ni < 4; ++ni)
        acc[mi][ni] = __builtin_amdgcn_mfma_f32_16x16x32_bf16(a1[mi], b1[ni], acc[mi][ni], 0, 0, 0);
    __builtin_amdgcn_s_setprio(0);

    if (pf)
      asm volatile("s_waitcnt vmcnt(6)" ::: "memory");
    else if (t + 2 == NT)
      asm volatile("s_waitcnt vmcnt(0)" ::: "memory");
    BARRIER();

    s = (s == 2) ? 0 : s + 1;
    s2 = (s2 == 2) ? 0 : s2 + 1;
  }

#pragma unroll
  for (int ni = 0; ni < 4; ++ni) {
    int n = n0 + wn + ni * 16 + col;
    float bb = bproj[e * D + n];
#pragma unroll
    for (int mi = 0; mi < 4; ++mi) {
#pragma unroll
      for (int i = 0; i < 4; ++i) {
        int m = m0 + wm + mi * 16 + quad * 4 + i;
        out[(size_t)e * T * D + (size_t)m * D + n] = acc[mi][ni][i] + bb;
      }
    }
  }
}

// ---------------------------------------------------------------------------

extern "C" void kernel_launch(void* const* d_in, const int* in_sizes, int n_in,
                              void* d_out, int out_size, void* d_ws, size_t ws_size,
                              hipStream_t stream) {
  const float* x = (const float*)d_in[0];
  const float* wfc = (const float*)d_in[1];
  const float* bfc = (const float*)d_in[2];
  const float* wg = (const float*)d_in[3];
  const float* bg = (const float*)d_in[4];
  const float* wp = (const float*)d_in[5];
  const float* bp = (const float*)d_in[6];
  float* out = (float*)d_out;

  char* ws = (char*)d_ws;
  // ws layout (bytes): xb 32MB | wfcT 64MB | wgT 64MB | wpT 64MB | og 128MB
  unsigned short* xb = (unsigned short*)(ws);
  unsigned short* wfcT = (unsigned short*)(ws + 33554432);
  unsigned short* wgT = (unsigned short*)(ws + 100663296);
  unsigned short* wpT = (unsigned short*)(ws + 167772160);
  unsigned short* og = (unsigned short*)(ws + 234881024);

  convert_kernel<<<2048, 256, 0, stream>>>((const float4*)x, (ushort4*)xb,
                                           (int)((size_t)E * T * D / 4));
  tconv_kernel<<<dim3(H / 32, D / 32, E), dim3(32, 8), 0, stream>>>(wfc, wfcT, D, H);
  tconv_kernel<<<dim3(H / 32, D / 32, E), dim3(32, 8), 0, stream>>>(wg, wgT, D, H);
  tconv_kernel<<<dim3(D / 32, H / 32, E), dim3(32, 8), 0, stream>>>(wp, wpT, H, D);

  gemm1_kernel<<<E * (T / 128) * (H / 128), 512, 0, stream>>>(xb, wfcT, wgT, bfc, bg, og);
  gemm2_kernel<<<E * (T / 256) * (D / 128), 512, 0, stream>>>(og, wpT, bp, out);
}

// Round 3
// 863.584 us; speedup vs baseline: 1.2024x; 1.0233x over previous
//
#include <hip/hip_runtime.h>

#define E 8
#define T 2048
#define D 1024
#define H 4096

using f32x4 = __attribute__((ext_vector_type(4))) float;
using frag8 = __attribute__((ext_vector_type(8))) short;  // 8 bf16 in 4 VGPRs

typedef unsigned int uint_as3 __attribute__((address_space(3)));
typedef unsigned int uint_as1 __attribute__((address_space(1)));

__device__ __forceinline__ unsigned short f2bf(float f) {
  unsigned int u = __float_as_uint(f);
  u += 0x7fffu + ((u >> 16) & 1u);  // round-to-nearest-even
  return (unsigned short)(u >> 16);
}

__device__ __forceinline__ void gload16(const void* g, void* l) {
  __builtin_amdgcn_global_load_lds((const uint_as1*)g, (uint_as3*)l, 16, 0, 0);
}

// Stage 8 rows x 64 cols bf16 starting at row r0, one full wave (64 lanes x 16B).
// XOR-swizzle: LDS slot (row, cs) holds global chunk cs ^ (row&7). Since the
// LDS dest of global_load_lds is forced to base+lane*16, we permute the GLOBAL
// source chunk per lane instead. Verified: 0 bank conflicts in rocprof.
__device__ __forceinline__ void stage8(const unsigned short* src, int ld,
                                       unsigned short* lds, int r0, int lane) {
  int lr = lane >> 3;       // row within the 8-row chunk
  int cs = lane & 7;        // LDS chunk slot
  int gc = cs ^ lr;         // swizzled global chunk
  const unsigned short* g = src + (size_t)(r0 + lr) * ld + gc * 8;
  unsigned short* l = lds + r0 * 64;  // wave-uniform base
  gload16(g, l);
}

// Read a K-contiguous 8-elem bf16 fragment for `row` at chunk index, undoing
// the swizzle. 2-way bank aliasing only -> conflict-free (measured 0).
__device__ __forceinline__ frag8 read_frag(const unsigned short* lds, int row, int chunk) {
  return *(const frag8*)&lds[row * 64 + ((chunk ^ (row & 7)) << 3)];
}

#define BARRIER() asm volatile("s_barrier" ::: "memory")

// ---------------- pass 0: convert / transpose-convert to bf16 ----------------

__global__ __launch_bounds__(256) void convert_kernel(const float4* __restrict__ in,
                                                      ushort4* __restrict__ out, int n4) {
  int i = blockIdx.x * blockDim.x + threadIdx.x;
  int stride = gridDim.x * blockDim.x;
  for (; i < n4; i += stride) {
    float4 v = in[i];
    ushort4 o;
    o.x = f2bf(v.x); o.y = f2bf(v.y); o.z = f2bf(v.z); o.w = f2bf(v.w);
    out[i] = o;
  }
}

// per-expert [R,C] fp32 -> [C,R] bf16, 64x64 tiles, vectorized both sides.
// grid: (C/64, R/64, E), block 256.  Loads: float4 (fully coalesced).
// Stores: frag8 16B -> 8 lanes x 16B = 128B contiguous per output column group.
__global__ __launch_bounds__(256) void tconv_kernel(const float* __restrict__ in,
                                                    unsigned short* __restrict__ out,
                                                    int R, int C) {
  __shared__ unsigned short tile[64][72];  // [c][r], stride 144B (16B-aligned)
  int e = blockIdx.z;
  const float* src = in + (size_t)e * R * C;
  unsigned short* dst = out + (size_t)e * R * C;
  int c0 = blockIdx.x * 64, r0 = blockIdx.y * 64;
  int tid = threadIdx.x;
  int lr = tid >> 4;        // 0..15
  int lc = (tid & 15) * 4;  // 0..60
#pragma unroll
  for (int i = 0; i < 4; ++i) {
    float4 v = *(const float4*)&src[(size_t)(r0 + lr + i * 16) * C + c0 + lc];
    tile[lc + 0][lr + i * 16] = f2bf(v.x);
    tile[lc + 1][lr + i * 16] = f2bf(v.y);
    tile[lc + 2][lr + i * 16] = f2bf(v.z);
    tile[lc + 3][lr + i * 16] = f2bf(v.w);
  }
  __syncthreads();
  int sc = tid >> 3;        // 0..31
  int sr = (tid & 7) * 8;   // 0..56
#pragma unroll
  for (int i = 0; i < 2; ++i) {
    int c = sc + i * 32;
    frag8 v = *(const frag8*)&tile[c][sr];
    *(frag8*)&dst[(size_t)(c0 + c) * R + r0 + sr] = v;
  }
}

// ---------------- GEMM1: og = (x@Wfc + bfc) * silu(x@Wg + bg) ----------------
// 2-slot LDS ring (classic dbuf, stage-at-top), ONE barrier per K-tile, 8 waves.
// BM=256, BN=128 (cols of both h and g). Waves 4M x 2N, per-wave 64x64 of BOTH
// mats: acc = 2*(4x4)*4 = 128 VGPR; 64 MFMA / K-tile / wave.
// LDS traffic/tile: A 32K*2 + B 32K*4 reads + 64K writes = 256KB per 8.39 MFLOP
// (30.5 B/KFLOP, vs 42 in the 128x128 shape) -> LDS-BW ceiling ~68% MfmaUtil.
// Race-freedom: iter t reads slot t&1, stages t+1 into slot (t+1)&1 whose last
// readers were iter t-1 (sealed by that iter's end barrier). vmcnt(0)+barrier
// at iter end publishes tile t+1; loads were issued a full tile earlier.

__global__ __launch_bounds__(512) void gemm1_kernel(
    const unsigned short* __restrict__ xb,
    const unsigned short* __restrict__ wfcT,
    const unsigned short* __restrict__ wgT,
    const float* __restrict__ bfc,
    const float* __restrict__ bgate,
    unsigned short* __restrict__ og) {
  __shared__ unsigned short As[2][256 * 64];  // 2 x 32 KB
  __shared__ unsigned short Bf[2][128 * 64];  // 2 x 16 KB
  __shared__ unsigned short Bg[2][128 * 64];  // 2 x 16 KB   total 128 KB

  int bid = blockIdx.x;
  int e = bid & 7;            // XCD-aligned: one expert per XCD
  int idx = bid >> 3;         // 0..255
  int mt = idx & 7;           // T/256 = 8  (mt inner: weight panels reused in L2)
  int nt = idx >> 3;          // H/128 = 32
  int m0 = mt * 256, n0 = nt * 128;

  int tid = threadIdx.x;
  int w = __builtin_amdgcn_readfirstlane(tid >> 6);
  int lane = tid & 63;

  const unsigned short* Ab = xb + (size_t)e * T * D + (size_t)m0 * D;
  const unsigned short* Fb = wfcT + (size_t)e * H * D + (size_t)n0 * D;
  const unsigned short* Gb = wgT + (size_t)e * H * D + (size_t)n0 * D;

  f32x4 ah[4][4] = {};
  f32x4 ag[4][4] = {};

  int wm = (w >> 1) * 64;   // 0,64,128,192
  int wn = (w & 1) * 64;    // 0,64
  int col = lane & 15, quad = lane >> 4;
  int r0a = w * 8;          // per-wave staging row base

  constexpr int NT = D / 64;  // 16 K-tiles

  // prologue: stage tile 0 into slot 0 (8 wave-loads)
  stage8(Ab, D, As[0], r0a, lane);
  stage8(Ab, D, As[0], r0a + 64, lane);
  stage8(Ab, D, As[0], r0a + 128, lane);
  stage8(Ab, D, As[0], r0a + 192, lane);
  stage8(Fb, D, Bf[0], r0a, lane);
  stage8(Fb, D, Bf[0], r0a + 64, lane);
  stage8(Gb, D, Bg[0], r0a, lane);
  stage8(Gb, D, Bg[0], r0a + 64, lane);
  asm volatile("s_waitcnt vmcnt(0)" ::: "memory");
  BARRIER();

  for (int t = 0; t < NT; ++t) {
    int s = t & 1;
    const unsigned short* Asl = As[s];
    const unsigned short* Bfl = Bf[s];
    const unsigned short* Bgl = Bg[s];

    // phase-0 frag reads (chunk = quad)
    frag8 a[4], f[4], g[4];
#pragma unroll
    for (int i = 0; i < 4; ++i) a[i] = read_frag(Asl, wm + i * 16 + col, quad);
#pragma unroll
    for (int i = 0; i < 4; ++i) f[i] = read_frag(Bfl, wn + i * 16 + col, quad);
#pragma unroll
    for (int i = 0; i < 4; ++i) g[i] = read_frag(Bgl, wn + i * 16 + col, quad);

    // stage tile t+1 into the other slot (issue-early; lands during compute)
    if (t + 1 < NT) {
      int kn = (t + 1) * 64, s2 = s ^ 1;
      stage8(Ab + kn, D, As[s2], r0a, lane);
      stage8(Ab + kn, D, As[s2], r0a + 64, lane);
      stage8(Ab + kn, D, As[s2], r0a + 128, lane);
      stage8(Ab + kn, D, As[s2], r0a + 192, lane);
      stage8(Fb + kn, D, Bf[s2], r0a, lane);
      stage8(Fb + kn, D, Bf[s2], r0a + 64, lane);
      stage8(Gb + kn, D, Bg[s2], r0a, lane);
      stage8(Gb + kn, D, Bg[s2], r0a + 64, lane);
    }

    __builtin_amdgcn_s_setprio(1);
#pragma unroll
    for (int mi = 0; mi < 4; ++mi)
#pragma unroll
      for (int ni = 0; ni < 4; ++ni) {
        ah[mi][ni] = __builtin_amdgcn_mfma_f32_16x16x32_bf16(a[mi], f[ni], ah[mi][ni], 0, 0, 0);
        ag[mi][ni] = __builtin_amdgcn_mfma_f32_16x16x32_bf16(a[mi], g[ni], ag[mi][ni], 0, 0, 0);
      }
    __builtin_amdgcn_s_setprio(0);

    // phase-1 frag reads (chunk = 4+quad)
    frag8 a1[4], f1[4], g1[4];
#pragma unroll
    for (int i = 0; i < 4; ++i) a1[i] = read_frag(Asl, wm + i * 16 + col, 4 + quad);
#pragma unroll
    for (int i = 0; i < 4; ++i) f1[i] = read_frag(Bfl, wn + i * 16 + col, 4 + quad);
#pragma unroll
    for (int i = 0; i < 4; ++i) g1[i] = read_frag(Bgl, wn + i * 16 + col, 4 + quad);

    __builtin_amdgcn_s_setprio(1);
#pragma unroll
    for (int mi = 0; mi < 4; ++mi)
#pragma unroll
      for (int ni = 0; ni < 4; ++ni) {
        ah[mi][ni] = __builtin_amdgcn_mfma_f32_16x16x32_bf16(a1[mi], f1[ni], ah[mi][ni], 0, 0, 0);
        ag[mi][ni] = __builtin_amdgcn_mfma_f32_16x16x32_bf16(a1[mi], g1[ni], ag[mi][ni], 0, 0, 0);
      }
    __builtin_amdgcn_s_setprio(0);

    asm volatile("s_waitcnt vmcnt(0)" ::: "memory");  // tile t+1 landed (issued ~1 tile ago)
    BARRIER();
  }

  // epilogue: bias + silu gate + product, write og bf16
#pragma unroll
  for (int ni = 0; ni < 4; ++ni) {
    int n = n0 + wn + ni * 16 + col;
    float bh = bfc[e * H + n];
    float bg2 = bgate[e * H + n];
#pragma unroll
    for (int mi = 0; mi < 4; ++mi) {
#pragma unroll
      for (int i = 0; i < 4; ++i) {
        int m = m0 + wm + mi * 16 + quad * 4 + i;
        float hv = ah[mi][ni][i] + bh;
        float gv = ag[mi][ni][i] + bg2;
        float sg = gv / (1.0f + __expf(-gv));
        og[(size_t)e * T * H + (size_t)m * H + n] = f2bf(hv * sg);
      }
    }
  }
}

// ---------------- GEMM2: out = og @ Wproj + bproj (fp32 out) ----------------
// Same 2-slot / single-barrier schedule. BM=256, BN=256, 8 waves 4M x 2N,
// per-wave 64x128: acc 128 VGPR, 64 MFMA / K-tile / wave. Grid = 256 blocks =
// exactly 1/CU. XCD swizzle: bid&7 = XCD = expert (og 16MB + wpT 8MB per XCD).

__global__ __launch_bounds__(512) void gemm2_kernel(
    const unsigned short* __restrict__ og,
    const unsigned short* __restrict__ wpT,
    const float* __restrict__ bproj,
    float* __restrict__ out) {
  __shared__ unsigned short As[2][256 * 64];  // 2 x 32 KB
  __shared__ unsigned short Bs[2][256 * 64];  // 2 x 32 KB   total 128 KB

  int bid = blockIdx.x;
  int e = bid & 7;            // XCD-aligned: one expert per XCD
  int idx = bid >> 3;         // 0..31
  int mt = idx & 7;           // T/256 = 8
  int nt = idx >> 3;          // D/256 = 4
  int m0 = mt * 256, n0 = nt * 256;

  int tid = threadIdx.x;
  int w = __builtin_amdgcn_readfirstlane(tid >> 6);
  int lane = tid & 63;

  const unsigned short* Ab = og + (size_t)e * T * H + (size_t)m0 * H;
  const unsigned short* Bb = wpT + (size_t)e * D * H + (size_t)n0 * H;

  f32x4 acc[4][8] = {};

  int wm = (w >> 1) * 64;   // 0,64,128,192
  int wn = (w & 1) * 128;   // 0,128
  int col = lane & 15, quad = lane >> 4;
  int r0a = w * 8;

  constexpr int NT = H / 64;  // 64 K-tiles

  // prologue: stage tile 0 into slot 0
  stage8(Ab, H, As[0], r0a, lane);
  stage8(Ab, H, As[0], r0a + 64, lane);
  stage8(Ab, H, As[0], r0a + 128, lane);
  stage8(Ab, H, As[0], r0a + 192, lane);
  stage8(Bb, H, Bs[0], r0a, lane);
  stage8(Bb, H, Bs[0], r0a + 64, lane);
  stage8(Bb, H, Bs[0], r0a + 128, lane);
  stage8(Bb, H, Bs[0], r0a + 192, lane);
  asm volatile("s_waitcnt vmcnt(0)" ::: "memory");
  BARRIER();

  for (int t = 0; t < NT; ++t) {
    int s = t & 1;
    const unsigned short* Asl = As[s];
    const unsigned short* Bsl = Bs[s];

    frag8 a[4], b[8];
#pragma unroll
    for (int i = 0; i < 4; ++i) a[i] = read_frag(Asl, wm + i * 16 + col, quad);
#pragma unroll
    for (int i = 0; i < 8; ++i) b[i] = read_frag(Bsl, wn + i * 16 + col, quad);

    if (t + 1 < NT) {
      int kn = (t + 1) * 64, s2 = s ^ 1;
      stage8(Ab + kn, H, As[s2], r0a, lane);
      stage8(Ab + kn, H, As[s2], r0a + 64, lane);
      stage8(Ab + kn, H, As[s2], r0a + 128, lane);
      stage8(Ab + kn, H, As[s2], r0a + 192, lane);
      stage8(Bb + kn, H, Bs[s2], r0a, lane);
      stage8(Bb + kn, H, Bs[s2], r0a + 64, lane);
      stage8(Bb + kn, H, Bs[s2], r0a + 128, lane);
      stage8(Bb + kn, H, Bs[s2], r0a + 192, lane);
    }

    __builtin_amdgcn_s_setprio(1);
#pragma unroll
    for (int mi = 0; mi < 4; ++mi)
#pragma unroll
      for (int ni = 0; ni < 8; ++ni)
        acc[mi][ni] = __builtin_amdgcn_mfma_f32_16x16x32_bf16(a[mi], b[ni], acc[mi][ni], 0, 0, 0);
    __builtin_amdgcn_s_setprio(0);

    frag8 a1[4], b1[8];
#pragma unroll
    for (int i = 0; i < 4; ++i) a1[i] = read_frag(Asl, wm + i * 16 + col, 4 + quad);
#pragma unroll
    for (int i = 0; i < 8; ++i) b1[i] = read_frag(Bsl, wn + i * 16 + col, 4 + quad);

    __builtin_amdgcn_s_setprio(1);
#pragma unroll
    for (int mi = 0; mi < 4; ++mi)
#pragma unroll
      for (int ni = 0; ni < 8; ++ni)
        acc[mi][ni] = __builtin_amdgcn_mfma_f32_16x16x32_bf16(a1[mi], b1[ni], acc[mi][ni], 0, 0, 0);
    __builtin_amdgcn_s_setprio(0);

    asm volatile("s_waitcnt vmcnt(0)" ::: "memory");
    BARRIER();
  }

#pragma unroll
  for (int ni = 0; ni < 8; ++ni) {
    int n = n0 + wn + ni * 16 + col;
    float bb = bproj[e * D + n];
#pragma unroll
    for (int mi = 0; mi < 4; ++mi) {
#pragma unroll
      for (int i = 0; i < 4; ++i) {
        int m = m0 + wm + mi * 16 + quad * 4 + i;
        out[(size_t)e * T * D + (size_t)m * D + n] = acc[mi][ni][i] + bb;
      }
    }
  }
}

// ---------------------------------------------------------------------------

extern "C" void kernel_launch(void* const* d_in, const int* in_sizes, int n_in,
                              void* d_out, int out_size, void* d_ws, size_t ws_size,
                              hipStream_t stream) {
  const float* x = (const float*)d_in[0];
  const float* wfc = (const float*)d_in[1];
  const float* bfc = (const float*)d_in[2];
  const float* wg = (const float*)d_in[3];
  const float* bg = (const float*)d_in[4];
  const float* wp = (const float*)d_in[5];
  const float* bp = (const float*)d_in[6];
  float* out = (float*)d_out;

  char* ws = (char*)d_ws;
  // ws layout (bytes): xb 32MB | wfcT 64MB | wgT 64MB | wpT 64MB | og 128MB
  unsigned short* xb = (unsigned short*)(ws);
  unsigned short* wfcT = (unsigned short*)(ws + 33554432);
  unsigned short* wgT = (unsigned short*)(ws + 100663296);
  unsigned short* wpT = (unsigned short*)(ws + 167772160);
  unsigned short* og = (unsigned short*)(ws + 234881024);

  convert_kernel<<<2048, 256, 0, stream>>>((const float4*)x, (ushort4*)xb,
                                           (int)((size_t)E * T * D / 4));
  tconv_kernel<<<dim3(H / 64, D / 64, E), 256, 0, stream>>>(wfc, wfcT, D, H);
  tconv_kernel<<<dim3(H / 64, D / 64, E), 256, 0, stream>>>(wg, wgT, D, H);
  tconv_kernel<<<dim3(D / 64, H / 64, E), 256, 0, stream>>>(wp, wpT, H, D);

  gemm1_kernel<<<E * (T / 256) * (H / 128), 512, 0, stream>>>(xb, wfcT, wgT, bfc, bg, og);
  gemm2_kernel<<<E * (T / 256) * (D / 256), 512, 0, stream>>>(og, wpT, bp, out);
}